// Round 6
// baseline (431.062 us; speedup 1.0000x reference)
//
#include <hip/hip_runtime.h>
#include <hip/hip_bf16.h>

#define G    96
#define G2   9216          // G*G
#define NN   884736        // G*G*G
#define NV   221184        // NN/4 (float4/uint4 elements)
#define NB4  864           // NV/256
#define GZ4  24            // G/4

typedef unsigned int  u32;
typedef unsigned char u8;

__device__ __forceinline__ float max3f(float a, float b, float c) {
    return fmaxf(fmaxf(a, b), c);
}

// ---------------------------------------------------------------------------
// Union-find primitives (ECL-CC style, root = MAX label of component).
// Labels are voxel_index+1; P[l-1] is l's parent; P value 0 = unmasked.
// Invariant: parent >= self; all updates monotone increasing => benign races.
// ---------------------------------------------------------------------------
__device__ __forceinline__ u32 findroot(u32* __restrict__ P, u32 a) {
    u32 p = P[a - 1];
    while (p != a) {                     // walk with path halving
        u32 gp = P[p - 1];
        if (gp != p) P[a - 1] = gp;      // benign race: gp is an ancestor
        a = p; p = gp;
    }
    return a;
}

__device__ __forceinline__ void merge(u32* __restrict__ P, u32 a, u32 b) {
    a = findroot(P, a);
    b = findroot(P, b);
    while (a != b) {
        if (a < b) { u32 t = a; a = b; b = t; }       // a > b: hook b under a
        u32 old = atomicCAS(&P[b - 1], b, a);          // only hooks live roots
        if (old == b) return;                          // success
        b = findroot(P, old);                          // raced: follow new chain
    }
}

// ---------------------------------------------------------------------------
// k_prep_pz: fused elementwise prep + z-axis window-3 max pool (vectorized).
//   out0 = 1-exp(-0.01*relu(den)); out3 = max(0.8*cac, relu(den));
//   zp   = z-pool3 of field(out3). Also zeroes the last-block done counter.
// ---------------------------------------------------------------------------
__global__ void k_prep_pz(const float* __restrict__ den, const float* __restrict__ cac,
                          float* __restrict__ out0, float* __restrict__ out3,
                          float* __restrict__ zp, u32* __restrict__ done) {
    int V = blockIdx.x * blockDim.x + threadIdx.x;   // 0..NV
    if (V == 0) *done = 0u;
    if (V >= NV) return;
    int z4 = V % GZ4;
    int v0 = V * 4;

    float4 d4 = ((const float4*)den)[V];
    float4 c4 = ((const float4*)cac)[V];
    float d[4] = {d4.x, d4.y, d4.z, d4.w};
    float c[4] = {c4.x, c4.y, c4.z, c4.w};

    float f[6];                                      // field at z0-1 .. z0+4
    #pragma unroll
    for (int i = 0; i < 4; ++i) {
        float dd = d[i] > 0.0f ? d[i] : 0.0f;
        float nc = fmaxf(c[i] * 0.8f, dd);
        d[i] = dd; c[i] = nc;
        f[i + 1] = 1.0f - __expf(-0.01f * nc);
    }
    if (z4 > 0) {
        float dd = den[v0 - 1]; dd = dd > 0.0f ? dd : 0.0f;
        float nc = fmaxf(cac[v0 - 1] * 0.8f, dd);
        f[0] = 1.0f - __expf(-0.01f * nc);
    } else f[0] = 0.0f;                              // zero pad (field >= 0)
    if (z4 < GZ4 - 1) {
        float dd = den[v0 + 4]; dd = dd > 0.0f ? dd : 0.0f;
        float nc = fmaxf(cac[v0 + 4] * 0.8f, dd);
        f[5] = 1.0f - __expf(-0.01f * nc);
    } else f[5] = 0.0f;

    ((float4*)out0)[V] = make_float4(1.0f - __expf(-0.01f * d[0]),
                                     1.0f - __expf(-0.01f * d[1]),
                                     1.0f - __expf(-0.01f * d[2]),
                                     1.0f - __expf(-0.01f * d[3]));
    ((float4*)out3)[V] = make_float4(c[0], c[1], c[2], c[3]);
    ((float4*)zp)[V]   = make_float4(max3f(f[0], f[1], f[2]),
                                     max3f(f[1], f[2], f[3]),
                                     max3f(f[2], f[3], f[4]),
                                     max3f(f[3], f[4], f[5]));
}

// ---------------------------------------------------------------------------
// k_pyx_sum: fused y+x max pool (9-row window over z-pooled input) + per-block
// partial sums + counts zeroing + LAST-BLOCK finish:
//   thr = min(mean, 0.01) -> scal; zero key; sniff old_field dtype.
// ---------------------------------------------------------------------------
__global__ void k_pyx_sum(const float* __restrict__ in, float* __restrict__ out,
                          float* __restrict__ parts, u32* __restrict__ counts,
                          u32* __restrict__ done, const u32* __restrict__ oldw,
                          float* __restrict__ scal, unsigned long long* __restrict__ key,
                          u32* __restrict__ dtype) {
    __shared__ float sw[4];
    __shared__ int amLast;
    int V = blockIdx.x * blockDim.x + threadIdx.x;     // grid exactly NV threads
    ((uint4*)counts)[V] = make_uint4(0u, 0u, 0u, 0u);  // counts[0..NN-1]
    if (V == 0) counts[NN] = 0u;                       // counts[NN]

    int y = (V / GZ4) % G;
    int x = V / (GZ4 * G);
    int dy0 = (y > 0) ? -1 : 0, dy1 = (y < G - 1) ? 1 : 0;
    int dx0 = (x > 0) ? -1 : 0, dx1 = (x < G - 1) ? 1 : 0;
    float4 m = make_float4(0.0f, 0.0f, 0.0f, 0.0f);    // fields >= 0
    for (int dx = dx0; dx <= dx1; ++dx)
        for (int dy = dy0; dy <= dy1; ++dy) {
            float4 a = ((const float4*)in)[V + dx * GZ4 * G + dy * GZ4];
            m.x = fmaxf(m.x, a.x); m.y = fmaxf(m.y, a.y);
            m.z = fmaxf(m.z, a.z); m.w = fmaxf(m.w, a.w);
        }
    ((float4*)out)[V] = m;

    float s = (m.x + m.y) + (m.z + m.w);
    #pragma unroll
    for (int off = 32; off >= 1; off >>= 1) s += __shfl_xor(s, off, 64);
    if ((threadIdx.x & 63) == 0) sw[threadIdx.x >> 6] = s;
    __syncthreads();
    if (threadIdx.x == 0) {
        parts[blockIdx.x] = (sw[0] + sw[1]) + (sw[2] + sw[3]);
        __threadfence();
        u32 prev = atomicAdd(done, 1u);
        amLast = (prev == NB4 - 1) ? 1 : 0;
    }
    __syncthreads();
    if (!amLast) return;

    // ---- last block: finish ----
    __shared__ float sw2[4];
    __shared__ int s_nz, s_bad01, s_badF, s_odd;
    int t = threadIdx.x;
    if (t == 0) { s_nz = 0; s_bad01 = 0; s_badF = 0; s_odd = 0; *key = 0ull; }

    float ss = 0.0f;
    for (int i = t; i < NB4; i += 256) ss += parts[i];
    #pragma unroll
    for (int off = 32; off >= 1; off >>= 1) ss += __shfl_xor(ss, off, 64);
    if ((t & 63) == 0) sw2[t >> 6] = ss;

    int nz = 0, bad01 = 0, badF = 0, odd = 0;
    for (int i = t; i < 4096; i += 256) {              // first 16 KB of old_field
        u32 xw = oldw[i];
        if (xw != 0u) {
            nz = 1;
            if (xw != 1u)          bad01 = 1;
            if (xw != 0x3F800000u) badF  = 1;
            if (xw & 0xFFFFFF00u)  odd   = 1;
        }
    }
    __syncthreads();
    if (nz)    atomicOr(&s_nz, 1);
    if (bad01) atomicOr(&s_bad01, 1);
    if (badF)  atomicOr(&s_badF, 1);
    if (odd)   atomicOr(&s_odd, 1);
    __syncthreads();
    if (t == 0) {
        float total = (sw2[0] + sw2[1]) + (sw2[2] + sw2[3]);
        scal[0] = fminf(total * (1.0f / (float)NN), 0.01f);
        u32 dt;
        if (!s_nz)         dt = 0u;                    // 0=bool u8
        else if (!s_bad01) dt = s_odd ? 0u : 1u;       // 1=int32
        else if (!s_badF)  dt = 2u;                    // 2=float32
        else               dt = 0u;
        *dtype = dt;
    }
}

// ---------------------------------------------------------------------------
// k_init: P[v] = pooled[v] > thr ? v+1 : 0  (each masked voxel its own root).
// ---------------------------------------------------------------------------
__global__ void k_init(const float* __restrict__ pooled, const float* __restrict__ scal,
                       u32* __restrict__ P) {
    int V = blockIdx.x * blockDim.x + threadIdx.x;
    if (V >= NV) return;
    float thr = scal[0];
    float4 p = ((const float4*)pooled)[V];
    int v0 = V * 4;
    uint4 c;
    c.x = p.x > thr ? (u32)(v0 + 1) : 0u;
    c.y = p.y > thr ? (u32)(v0 + 2) : 0u;
    c.z = p.z > thr ? (u32)(v0 + 3) : 0u;
    c.w = p.w > thr ? (u32)(v0 + 4) : 0u;
    ((uint4*)P)[V] = c;
}

// ---------------------------------------------------------------------------
// k_union: one pass over all 26-connectivity edges (13 forward dirs per voxel,
// positive-lexicographic => each edge visited exactly once). Lock-free
// union-find; after this kernel every masked voxel's root = component max.
// ---------------------------------------------------------------------------
__global__ void k_union(u32* __restrict__ P) {
    int V = blockIdx.x * blockDim.x + threadIdx.x;
    if (V >= NV) return;
    int z4 = V % GZ4;
    int tt = V / GZ4;
    int y  = tt % G;
    int x  = tt / G;
    int v0 = V * 4;

    uint4 p4 = ((const uint4*)P)[V];
    u32 p[4] = {p4.x, p4.y, p4.z, p4.w};

    // +z edges inside the quad
    if (p[0] && p[1]) merge(P, p[0], p[1]);
    if (p[1] && p[2]) merge(P, p[1], p[2]);
    if (p[2] && p[3]) merge(P, p[2], p[3]);
    // +z edge to the next quad
    if (z4 < GZ4 - 1 && p[3]) {
        u32 w = P[v0 + 4];
        if (w && w != p[3]) merge(P, p[3], w);
    }

    // lateral windows: dy=+1 (dx=0), and dx=+1 with dy in {-1,0,+1}.
    // window covers neighbor z-offsets -1..+4 relative to quad start.
    int offs[4];
    int nw = 0;
    if (y < G - 1) offs[nw++] = G;                       // (0,+1,*)
    if (x < G - 1) {
        if (y > 0)     offs[nw++] = G2 - G;              // (+1,-1,*)
        offs[nw++] = G2;                                 // (+1, 0,*)
        if (y < G - 1) offs[nw++] = G2 + G;              // (+1,+1,*)
    }
    for (int k = 0; k < nw; ++k) {
        int base = v0 + offs[k];
        uint4 mq = *(const uint4*)(P + base);
        u32 win[6];
        win[0] = (z4 > 0)       ? P[base - 1] : 0u;
        win[1] = mq.x; win[2] = mq.y; win[3] = mq.z; win[4] = mq.w;
        win[5] = (z4 < GZ4 - 1) ? P[base + 4] : 0u;
        #pragma unroll
        for (int i = 0; i < 4; ++i) {
            if (!p[i]) continue;
            #pragma unroll
            for (int dz = 0; dz < 3; ++dz) {
                u32 w = win[i + dz];
                if (w && w != p[i]) merge(P, p[i], w);
            }
        }
    }
}

// ---------------------------------------------------------------------------
// k_flat_hist: full path compression (P[v] = root) + histogram via per-thread
// run-length + wave reduce-by-key (one dominant component => ~1 atomic/wave).
// ---------------------------------------------------------------------------
__global__ void k_flat_hist(u32* __restrict__ P, u32* __restrict__ counts) {
    int V = blockIdx.x * blockDim.x + threadIdx.x;
    if (V >= NV) return;
    uint4 p4 = ((const uint4*)P)[V];
    uint4 r;
    r.x = p4.x ? findroot(P, p4.x) : 0u;
    r.y = p4.y ? findroot(P, p4.y) : 0u;
    r.z = p4.z ? findroot(P, p4.z) : 0u;
    r.w = p4.w ? findroot(P, p4.w) : 0u;
    ((uint4*)P)[V] = r;                      // full compression: P becomes comp

    u32 l[4] = {r.x, r.y, r.z, r.w};
    u32 mylab = 0, mycnt = 0;
    #pragma unroll
    for (int i = 0; i < 4; ++i) {
        u32 lab = l[i];
        if (lab != mylab) {
            if (mylab) atomicAdd(&counts[mylab], mycnt);
            mylab = lab; mycnt = 0;
        }
        if (lab) ++mycnt;
    }
    while (__any(mylab != 0)) {
        unsigned long long ball = __ballot(mylab != 0);
        int leader = (int)(__ffsll(ball) - 1);
        u32 llab = __shfl(mylab, leader, 64);
        bool mine = (mylab == llab);
        u32 cc = mine ? mycnt : 0u;
        #pragma unroll
        for (int off = 32; off >= 1; off >>= 1) cc += __shfl_xor(cc, off, 64);
        if ((int)(threadIdx.x & 63) == leader) atomicAdd(&counts[llab], cc);
        if (mine) mylab = 0;
    }
}

// ---------------------------------------------------------------------------
// k_argmax: argmax over counts[1..NN], ties -> smallest label; 1 atomic/block.
// ---------------------------------------------------------------------------
__global__ void k_argmax(const u32* __restrict__ counts, unsigned long long* key) {
    __shared__ unsigned long long sb[4];
    int i0 = blockIdx.x * blockDim.x + threadIdx.x;
    int stride = gridDim.x * blockDim.x;
    unsigned long long best = 0ull;
    for (int l = 1 + i0; l <= NN; l += stride) {
        unsigned long long k = ((unsigned long long)counts[l] << 32)
                             | (unsigned long long)(0xFFFFFFFFu - (u32)l);
        if (k > best) best = k;
    }
    #pragma unroll
    for (int off = 32; off >= 1; off >>= 1) {
        unsigned long long o = __shfl_xor(best, off, 64);
        if (o > best) best = o;
    }
    if ((threadIdx.x & 63) == 0) sb[threadIdx.x >> 6] = best;
    __syncthreads();
    if (threadIdx.x == 0) {
        unsigned long long b = sb[0];
        if (sb[1] > b) b = sb[1];
        if (sb[2] > b) b = sb[2];
        if (sb[3] > b) b = sb[3];
        atomicMax(key, b);
    }
}

// ---------------------------------------------------------------------------
// k_final: new_field = (comp == label); valid per step / old_field dtype.
// ---------------------------------------------------------------------------
__global__ void k_final(const u32* __restrict__ comp, const unsigned long long* __restrict__ key,
                        const u32* __restrict__ dtype, const void* __restrict__ oldf,
                        const int* __restrict__ step,
                        float* __restrict__ out_valid, float* __restrict__ out_nf) {
    int V = blockIdx.x * blockDim.x + threadIdx.x;
    if (V >= NV) return;
    u32 label = 0xFFFFFFFFu - (u32)((*key) & 0xFFFFFFFFull);
    int s = *step;
    u32 dt = *dtype;
    uint4 c = ((const uint4*)comp)[V];
    float4 nf = make_float4(c.x == label ? 1.0f : 0.0f,
                            c.y == label ? 1.0f : 0.0f,
                            c.z == label ? 1.0f : 0.0f,
                            c.w == label ? 1.0f : 0.0f);
    ((float4*)out_nf)[V] = nf;
    float4 val;
    if (s < 500) {
        val = nf;
    } else if (dt == 0) {
        u32 b4 = ((const u32*)oldf)[V];
        val = make_float4((b4 & 0xFFu) ? 1.0f : 0.0f,
                          (b4 & 0xFF00u) ? 1.0f : 0.0f,
                          (b4 & 0xFF0000u) ? 1.0f : 0.0f,
                          (b4 & 0xFF000000u) ? 1.0f : 0.0f);
    } else if (dt == 1) {
        uint4 w = ((const uint4*)oldf)[V];
        val = make_float4(w.x ? 1.0f : 0.0f, w.y ? 1.0f : 0.0f,
                          w.z ? 1.0f : 0.0f, w.w ? 1.0f : 0.0f);
    } else {
        val = ((const float4*)oldf)[V];
    }
    ((float4*)out_valid)[V] = val;
}

// ---------------------------------------------------------------------------
extern "C" void kernel_launch(void* const* d_in, const int* in_sizes, int n_in,
                              void* d_out, int out_size, void* d_ws, size_t ws_size,
                              hipStream_t stream) {
    const float* den  = (const float*)d_in[0];
    const float* cac  = (const float*)d_in[1];
    const void*  oldf = d_in[2];
    const int*   step = (const int*)d_in[3];

    float* out0 = (float*)d_out;        // out_density
    float* out1 = out0 + NN;            // valid
    float* out2 = out1 + NN;            // new_field
    float* out3 = out2 + NN;            // new_cached

    // ws: [0] scal | [8] key | [16] dtype | [20] done | [512] parts[864]
    //     [8192] A | +SZ B | +2SZ C   (SZ = (NN+16)*4)
    const size_t SZ = (size_t)(NN + 16) * 4;
    float*              scal  = (float*)d_ws;
    unsigned long long* key   = (unsigned long long*)((char*)d_ws + 8);
    u32*                dtype = (u32*)((char*)d_ws + 16);
    u32*                done  = (u32*)((char*)d_ws + 20);
    float*              parts = (float*)((char*)d_ws + 512);
    float* A = (float*)((char*)d_ws + 8192);            // zp -> parents/comp
    float* B = (float*)((char*)d_ws + 8192 + SZ);       // pooled field
    u32*   C = (u32*)  ((char*)d_ws + 8192 + 2 * SZ);   // counts

    u32* P = (u32*)A;

    const dim3 blk(256);

    k_prep_pz  <<<NB4, blk, 0, stream>>>(den, cac, out0, out3, A, done);
    k_pyx_sum  <<<NB4, blk, 0, stream>>>(A, B, parts, C, done, (const u32*)oldf,
                                         scal, key, dtype);
    k_init     <<<NB4, blk, 0, stream>>>(B, scal, P);
    k_union    <<<NB4, blk, 0, stream>>>(P);
    k_flat_hist<<<NB4, blk, 0, stream>>>(P, C);
    k_argmax   <<<128, blk, 0, stream>>>(C, key);
    k_final    <<<NB4, blk, 0, stream>>>(P, key, dtype, oldf, step, out1, out2);
}

// Round 7
// 131.597 us; speedup vs baseline: 3.2756x; 3.2756x over previous
//
#include <hip/hip_runtime.h>
#include <hip/hip_bf16.h>

#define G    96
#define G2   9216          // G*G
#define NN   884736        // G*G*G
#define NV   221184        // NN/4 (float4/uint4 elements)
#define NB4  864           // NV/256
#define GZ4  24            // G/4
#define ROUNDS 8           // dilate+jump rounds; horizon ~x7 per round

typedef unsigned int  u32;
typedef unsigned char u8;

__device__ __forceinline__ float max3f(float a, float b, float c) {
    return fmaxf(fmaxf(a, b), c);
}
__device__ __forceinline__ u32 max3u(u32 a, u32 b, u32 c) {
    u32 m = a > b ? a : b; return m > c ? m : c;
}
// depth-6 monotone pointer chase (valid: src[a-1] >= a for masked labels)
__device__ __forceinline__ u32 chase6(const u32* __restrict__ src, u32 a) {
    a = src[a-1]; a = src[a-1]; a = src[a-1];
    a = src[a-1]; a = src[a-1]; a = src[a-1];
    return a;
}

// ---------------------------------------------------------------------------
// k_prep_pz: fused elementwise prep + z-axis window-3 max pool (vectorized).
//   out0 = 1-exp(-0.01*relu(den)); out3 = max(0.8*cac, relu(den));
//   zp   = z-pool3 of field(out3).  Field recomputed for z-halo (cheap exp).
// ---------------------------------------------------------------------------
__global__ void k_prep_pz(const float* __restrict__ den, const float* __restrict__ cac,
                          float* __restrict__ out0, float* __restrict__ out3,
                          float* __restrict__ zp) {
    int V = blockIdx.x * blockDim.x + threadIdx.x;   // 0..NV
    if (V >= NV) return;
    int z4 = V % GZ4;
    int v0 = V * 4;

    float4 d4 = ((const float4*)den)[V];
    float4 c4 = ((const float4*)cac)[V];
    float d[4] = {d4.x, d4.y, d4.z, d4.w};
    float c[4] = {c4.x, c4.y, c4.z, c4.w};

    float f[6];                                      // field at z0-1 .. z0+4
    #pragma unroll
    for (int i = 0; i < 4; ++i) {
        float dd = d[i] > 0.0f ? d[i] : 0.0f;
        float nc = fmaxf(c[i] * 0.8f, dd);
        d[i] = dd; c[i] = nc;
        f[i + 1] = 1.0f - __expf(-0.01f * nc);
    }
    if (z4 > 0) {
        float dd = den[v0 - 1]; dd = dd > 0.0f ? dd : 0.0f;
        float nc = fmaxf(cac[v0 - 1] * 0.8f, dd);
        f[0] = 1.0f - __expf(-0.01f * nc);
    } else f[0] = 0.0f;                              // zero pad (field >= 0)
    if (z4 < GZ4 - 1) {
        float dd = den[v0 + 4]; dd = dd > 0.0f ? dd : 0.0f;
        float nc = fmaxf(cac[v0 + 4] * 0.8f, dd);
        f[5] = 1.0f - __expf(-0.01f * nc);
    } else f[5] = 0.0f;

    ((float4*)out0)[V] = make_float4(1.0f - __expf(-0.01f * d[0]),
                                     1.0f - __expf(-0.01f * d[1]),
                                     1.0f - __expf(-0.01f * d[2]),
                                     1.0f - __expf(-0.01f * d[3]));
    ((float4*)out3)[V] = make_float4(c[0], c[1], c[2], c[3]);
    ((float4*)zp)[V]   = make_float4(max3f(f[0], f[1], f[2]),
                                     max3f(f[1], f[2], f[3]),
                                     max3f(f[2], f[3], f[4]),
                                     max3f(f[3], f[4], f[5]));
}

// ---------------------------------------------------------------------------
// k_pyx_sum: fused y+x max pool (9-row window over z-pooled input) + per-block
// partial sums (no atomics) + zeroing of the counts histogram.
// ---------------------------------------------------------------------------
__global__ void k_pyx_sum(const float* __restrict__ in, float* __restrict__ out,
                          float* __restrict__ parts, u32* __restrict__ counts) {
    __shared__ float sw[4];
    int V = blockIdx.x * blockDim.x + threadIdx.x;   // grid exactly NV threads
    ((uint4*)counts)[V] = make_uint4(0u, 0u, 0u, 0u);  // counts[0..NN-1]
    if (V == 0) counts[NN] = 0u;                       // counts[NN]

    int y = (V / GZ4) % G;
    int x = V / (GZ4 * G);
    int dy0 = (y > 0) ? -1 : 0, dy1 = (y < G - 1) ? 1 : 0;
    int dx0 = (x > 0) ? -1 : 0, dx1 = (x < G - 1) ? 1 : 0;
    float4 m = make_float4(0.0f, 0.0f, 0.0f, 0.0f);   // fields >= 0
    for (int dx = dx0; dx <= dx1; ++dx)
        for (int dy = dy0; dy <= dy1; ++dy) {
            float4 a = ((const float4*)in)[V + dx * GZ4 * G + dy * GZ4];
            m.x = fmaxf(m.x, a.x); m.y = fmaxf(m.y, a.y);
            m.z = fmaxf(m.z, a.z); m.w = fmaxf(m.w, a.w);
        }
    ((float4*)out)[V] = m;

    float s = (m.x + m.y) + (m.z + m.w);
    #pragma unroll
    for (int off = 32; off >= 1; off >>= 1) s += __shfl_xor(s, off, 64);
    if ((threadIdx.x & 63) == 0) sw[threadIdx.x >> 6] = s;
    __syncthreads();
    if (threadIdx.x == 0) parts[blockIdx.x] = (sw[0] + sw[1]) + (sw[2] + sw[3]);
}

// ---------------------------------------------------------------------------
// k_finish (1 block): sum partials -> thr = min(mean,0.01); zero key/flags;
// sniff old_field dtype (0=bool u8, 1=int32, 2=float32).
// ---------------------------------------------------------------------------
__global__ void k_finish(const float* __restrict__ parts, const u32* __restrict__ oldw,
                         float* __restrict__ scal, unsigned long long* __restrict__ key,
                         u32* __restrict__ flags, u32* __restrict__ dtype) {
    __shared__ float sw[4];
    __shared__ int s_nz, s_bad01, s_badF, s_odd;
    int t = threadIdx.x;
    if (t == 0) { s_nz = 0; s_bad01 = 0; s_badF = 0; s_odd = 0; *key = 0ull; }
    if (t < 64) flags[t] = 0u;

    float s = 0.0f;
    for (int i = t; i < NB4; i += 256) s += parts[i];
    #pragma unroll
    for (int off = 32; off >= 1; off >>= 1) s += __shfl_xor(s, off, 64);
    if ((t & 63) == 0) sw[t >> 6] = s;

    int nz = 0, bad01 = 0, badF = 0, odd = 0;
    for (int i = t; i < 4096; i += 256) {            // first 16 KB of old_field
        u32 x = oldw[i];
        if (x != 0u) {
            nz = 1;
            if (x != 1u)          bad01 = 1;
            if (x != 0x3F800000u) badF  = 1;
            if (x & 0xFFFFFF00u)  odd   = 1;
        }
    }
    __syncthreads();
    if (nz)    atomicOr(&s_nz, 1);
    if (bad01) atomicOr(&s_bad01, 1);
    if (badF)  atomicOr(&s_badF, 1);
    if (odd)   atomicOr(&s_odd, 1);
    __syncthreads();
    if (t == 0) {
        float total = (sw[0] + sw[1]) + (sw[2] + sw[3]);
        scal[0] = fminf(total * (1.0f / (float)NN), 0.01f);
        u32 dt;
        if (!s_nz)         dt = 0u;
        else if (!s_bad01) dt = s_odd ? 0u : 1u;
        else if (!s_badF)  dt = 2u;
        else               dt = 0u;
        *dtype = dt;
    }
}

// ---------------------------------------------------------------------------
// k_dilate0: fused threshold + first 27-neighbor dilation, reading the pooled
// FLOAT field directly. cand per row = highest-index element passing thr.
// Seeds: id v+1 where pooled[v] > thr. Writes u32 comp; sets chgD[0].
// ---------------------------------------------------------------------------
__global__ void k_dilate0(const float* __restrict__ pf, const float* __restrict__ scal,
                          u32* __restrict__ dst, u32* __restrict__ chgD) {
    int V = blockIdx.x * blockDim.x + threadIdx.x;
    float thr = scal[0];                             // >= 0
    int z4 = V % GZ4;
    int tt = V / GZ4;
    int y  = tt % G;
    int x  = tt / G;
    int v0 = V * 4;

    float4 p = ((const float4*)pf)[V];
    u32 s0 = p.x > thr ? (u32)(v0 + 1) : 0u;
    u32 s1 = p.y > thr ? (u32)(v0 + 2) : 0u;
    u32 s2 = p.z > thr ? (u32)(v0 + 3) : 0u;
    u32 s3 = p.w > thr ? (u32)(v0 + 4) : 0u;

    u32 b0 = 0, b1 = 0, b2 = 0, b3 = 0;
    int dx0 = (x > 0) ? -1 : 0, dx1 = (x < G - 1) ? 1 : 0;
    int dy0 = (y > 0) ? -1 : 0, dy1 = (y < G - 1) ? 1 : 0;
    for (int dx = dx0; dx <= dx1; ++dx)
        for (int dy = dy0; dy <= dy1; ++dy) {
            int base = v0 + dx * G2 + dy * G;         // element index of m.x
            float4 m = *(const float4*)(pf + base);
            float pl = (z4 > 0)       ? pf[base - 1] : -1.0f;
            float pr = (z4 < GZ4 - 1) ? pf[base + 4] : -1.0f;
            // ids: pl->base, m.x->base+1, ..., m.w->base+4, pr->base+5
            u32 c0 = m.y > thr ? (u32)(base + 2) : m.x > thr ? (u32)(base + 1)
                   : pl  > thr ? (u32)(base)     : 0u;
            u32 c1 = m.z > thr ? (u32)(base + 3) : m.y > thr ? (u32)(base + 2)
                   : m.x > thr ? (u32)(base + 1) : 0u;
            u32 c2 = m.w > thr ? (u32)(base + 4) : m.z > thr ? (u32)(base + 3)
                   : m.y > thr ? (u32)(base + 2) : 0u;
            u32 c3 = pr  > thr ? (u32)(base + 5) : m.w > thr ? (u32)(base + 4)
                   : m.z > thr ? (u32)(base + 3) : 0u;
            b0 = b0 > c0 ? b0 : c0;
            b1 = b1 > c1 ? b1 : c1;
            b2 = b2 > c2 ? b2 : c2;
            b3 = b3 > c3 ? b3 : c3;
        }
    uint4 o;
    o.x = s0 ? b0 : 0u;
    o.y = s1 ? b1 : 0u;
    o.z = s2 ? b2 : 0u;
    o.w = s3 ? b3 : 0u;
    ((uint4*)dst)[V] = o;
    u32 ch = (o.x != s0) | (o.y != s1) | (o.z != s2) | (o.w != s3);
    if (__any(ch) && (threadIdx.x & 63) == 0) chgD[0] = 1u;
}

// ---------------------------------------------------------------------------
// k_dilate (r>=1): masked 27-neighbor max-dilation on u32 labels.
// Self-skips once a whole round made no changes (sticky => fixpoint held).
// ---------------------------------------------------------------------------
__global__ void k_dilate(const u32* __restrict__ src, u32* __restrict__ dst,
                         const u32* __restrict__ chgD, const u32* __restrict__ chgJ,
                         u32* __restrict__ myflag, int r) {
    if ((chgD[r - 1] | chgJ[r - 1]) == 0u) return;
    int V = blockIdx.x * blockDim.x + threadIdx.x;
    int z4 = V % GZ4;
    int tt = V / GZ4;
    int y  = tt % G;
    int x  = tt / G;
    int v0 = V * 4;

    uint4 c = ((const uint4*)src)[V];
    u32 b0 = 0, b1 = 0, b2 = 0, b3 = 0;
    int dx0 = (x > 0) ? -1 : 0, dx1 = (x < G - 1) ? 1 : 0;
    int dy0 = (y > 0) ? -1 : 0, dy1 = (y < G - 1) ? 1 : 0;
    for (int dx = dx0; dx <= dx1; ++dx)
        for (int dy = dy0; dy <= dy1; ++dy) {
            int base = v0 + dx * G2 + dy * G;
            uint4 m = *(const uint4*)(src + base);
            u32 pl = (z4 > 0)       ? src[base - 1] : 0u;
            u32 pr = (z4 < GZ4 - 1) ? src[base + 4] : 0u;
            u32 c0 = max3u(pl, m.x, m.y);
            u32 c1 = max3u(m.x, m.y, m.z);
            u32 c2 = max3u(m.y, m.z, m.w);
            u32 c3 = max3u(m.z, m.w, pr);
            b0 = b0 > c0 ? b0 : c0;
            b1 = b1 > c1 ? b1 : c1;
            b2 = b2 > c2 ? b2 : c2;
            b3 = b3 > c3 ? b3 : c3;
        }
    uint4 o;
    o.x = c.x ? b0 : 0u;
    o.y = c.y ? b1 : 0u;
    o.z = c.z ? b2 : 0u;
    o.w = c.w ? b3 : 0u;
    ((uint4*)dst)[V] = o;
    u32 ch = (o.x != c.x) | (o.y != c.y) | (o.z != c.z) | (o.w != c.w);
    if (__any(ch) && (threadIdx.x & 63) == 0) myflag[r] = 1u;
}

// ---------------------------------------------------------------------------
// k_jump: depth-6 pointer chase. For masked labels, src[a-1] >= a always
// (labels are >= own id, monotone max updates), so each chase is a plain
// reassignment — monotone and component-preserving. 4 independent chains/thread.
// ---------------------------------------------------------------------------
__global__ void k_jump(const u32* __restrict__ src, u32* __restrict__ dst,
                       const u32* __restrict__ chgD, const u32* __restrict__ chgJ,
                       u32* __restrict__ myflag, int r) {
    if (r > 0 && (chgD[r - 1] | chgJ[r - 1]) == 0u) return;
    int V = blockIdx.x * blockDim.x + threadIdx.x;
    uint4 v4 = ((const uint4*)src)[V];
    uint4 o = v4;
    if (o.x) o.x = chase6(src, o.x);
    if (o.y) o.y = chase6(src, o.y);
    if (o.z) o.z = chase6(src, o.z);
    if (o.w) o.w = chase6(src, o.w);
    ((uint4*)dst)[V] = o;
    u32 ch = (o.x != v4.x) | (o.y != v4.y) | (o.z != v4.z) | (o.w != v4.w);
    if (__any(ch) && (threadIdx.x & 63) == 0) myflag[r] = 1u;
}

// ---------------------------------------------------------------------------
// k_hist: per-label counts via per-thread run-length + wave reduce-by-key.
// ---------------------------------------------------------------------------
__global__ void k_hist(const u32* __restrict__ comp, u32* __restrict__ counts) {
    int stride = gridDim.x * blockDim.x;
    u32 mylab = 0, mycnt = 0;
    for (int V = blockIdx.x * blockDim.x + threadIdx.x; V < NV; V += stride) {
        uint4 l4 = ((const uint4*)comp)[V];
        u32 l[4] = {l4.x, l4.y, l4.z, l4.w};
        #pragma unroll
        for (int i = 0; i < 4; ++i) {
            u32 lab = l[i];
            if (lab != mylab) {
                if (mylab) atomicAdd(&counts[mylab], mycnt);
                mylab = lab; mycnt = 0;
            }
            if (lab) ++mycnt;
        }
    }
    while (__any(mylab != 0)) {
        unsigned long long ball = __ballot(mylab != 0);
        int leader = (int)(__ffsll(ball) - 1);
        u32 llab = __shfl(mylab, leader, 64);
        bool mine = (mylab == llab);
        u32 cc = mine ? mycnt : 0u;
        #pragma unroll
        for (int off = 32; off >= 1; off >>= 1) cc += __shfl_xor(cc, off, 64);
        if ((int)(threadIdx.x & 63) == leader) atomicAdd(&counts[llab], cc);
        if (mine) mylab = 0;
    }
}

// ---------------------------------------------------------------------------
// k_argmax: argmax over counts[1..NN], ties -> smallest label; 1 atomic/block.
// ---------------------------------------------------------------------------
__global__ void k_argmax(const u32* __restrict__ counts, unsigned long long* key) {
    __shared__ unsigned long long sb[4];
    int i0 = blockIdx.x * blockDim.x + threadIdx.x;
    int stride = gridDim.x * blockDim.x;
    unsigned long long best = 0ull;
    for (int l = 1 + i0; l <= NN; l += stride) {
        unsigned long long k = ((unsigned long long)counts[l] << 32)
                             | (unsigned long long)(0xFFFFFFFFu - (u32)l);
        if (k > best) best = k;
    }
    #pragma unroll
    for (int off = 32; off >= 1; off >>= 1) {
        unsigned long long o = __shfl_xor(best, off, 64);
        if (o > best) best = o;
    }
    if ((threadIdx.x & 63) == 0) sb[threadIdx.x >> 6] = best;
    __syncthreads();
    if (threadIdx.x == 0) {
        unsigned long long b = sb[0];
        if (sb[1] > b) b = sb[1];
        if (sb[2] > b) b = sb[2];
        if (sb[3] > b) b = sb[3];
        atomicMax(key, b);
    }
}

// ---------------------------------------------------------------------------
// k_final: new_field = (comp == label); valid per step / old_field dtype.
// ---------------------------------------------------------------------------
__global__ void k_final(const u32* __restrict__ comp, const unsigned long long* __restrict__ key,
                        const u32* __restrict__ dtype, const void* __restrict__ oldf,
                        const int* __restrict__ step,
                        float* __restrict__ out_valid, float* __restrict__ out_nf) {
    int V = blockIdx.x * blockDim.x + threadIdx.x;
    if (V >= NV) return;
    u32 label = 0xFFFFFFFFu - (u32)((*key) & 0xFFFFFFFFull);
    int s = *step;
    u32 dt = *dtype;
    uint4 c = ((const uint4*)comp)[V];
    float4 nf = make_float4(c.x == label ? 1.0f : 0.0f,
                            c.y == label ? 1.0f : 0.0f,
                            c.z == label ? 1.0f : 0.0f,
                            c.w == label ? 1.0f : 0.0f);
    ((float4*)out_nf)[V] = nf;
    float4 val;
    if (s < 500) {
        val = nf;
    } else if (dt == 0) {
        u32 b4 = ((const u32*)oldf)[V];
        val = make_float4((b4 & 0xFFu) ? 1.0f : 0.0f,
                          (b4 & 0xFF00u) ? 1.0f : 0.0f,
                          (b4 & 0xFF0000u) ? 1.0f : 0.0f,
                          (b4 & 0xFF000000u) ? 1.0f : 0.0f);
    } else if (dt == 1) {
        uint4 w = ((const uint4*)oldf)[V];
        val = make_float4(w.x ? 1.0f : 0.0f, w.y ? 1.0f : 0.0f,
                          w.z ? 1.0f : 0.0f, w.w ? 1.0f : 0.0f);
    } else {
        val = ((const float4*)oldf)[V];
    }
    ((float4*)out_valid)[V] = val;
}

// ---------------------------------------------------------------------------
extern "C" void kernel_launch(void* const* d_in, const int* in_sizes, int n_in,
                              void* d_out, int out_size, void* d_ws, size_t ws_size,
                              hipStream_t stream) {
    const float* den  = (const float*)d_in[0];
    const float* cac  = (const float*)d_in[1];
    const void*  oldf = d_in[2];
    const int*   step = (const int*)d_in[3];

    float* out0 = (float*)d_out;        // out_density
    float* out1 = out0 + NN;            // valid
    float* out2 = out1 + NN;            // new_field
    float* out3 = out2 + NN;            // new_cached

    // ws: [0] scal | [8] key | [16] dtype | [32] flags[64] | [512] parts[864]
    //     [8192] A | +SZ B | +2SZ C      (SZ = (NN+16)*4 bytes)
    const size_t SZ = (size_t)(NN + 16) * 4;
    float*              scal  = (float*)d_ws;
    unsigned long long* key   = (unsigned long long*)((char*)d_ws + 8);
    u32*                dtype = (u32*)((char*)d_ws + 16);
    u32*                flags = (u32*)((char*)d_ws + 32);
    float*              parts = (float*)((char*)d_ws + 512);
    float* A = (float*)((char*)d_ws + 8192);            // zp -> comp ping (Au)
    float* B = (float*)((char*)d_ws + 8192 + SZ);       // pooled -> comp pong (Bu)
    u32*   C = (u32*)  ((char*)d_ws + 8192 + 2 * SZ);   // counts

    u32* Au = (u32*)A;
    u32* Bu = (u32*)B;
    u32* chgD = flags;          // [0..ROUNDS)
    u32* chgJ = flags + 32;     // [32..32+ROUNDS)

    const dim3 blk(256);

    k_prep_pz<<<NB4, blk, 0, stream>>>(den, cac, out0, out3, A);
    k_pyx_sum<<<NB4, blk, 0, stream>>>(A, B, parts, C);
    k_finish <<<1,   blk, 0, stream>>>(parts, (const u32*)oldf, scal, key, flags, dtype);

    // CCL: round 0 fuses thresholding; then jump6(Au->Bu) + dilate(Bu->Au) pairs.
    k_dilate0<<<NB4, blk, 0, stream>>>(B, scal, Au, chgD);
    k_jump   <<<NB4, blk, 0, stream>>>(Au, Bu, chgD, chgJ, chgJ, 0);
    for (int r = 1; r < ROUNDS; ++r) {
        k_dilate<<<NB4, blk, 0, stream>>>(Bu, Au, chgD, chgJ, chgD, r);
        k_jump  <<<NB4, blk, 0, stream>>>(Au, Bu, chgD, chgJ, chgJ, r);
    }

    k_hist  <<<128, blk, 0, stream>>>(Bu, C);
    k_argmax<<<128, blk, 0, stream>>>(C, key);
    k_final <<<NB4, blk, 0, stream>>>(Bu, key, dtype, oldf, step, out1, out2);
}